// Round 1
// baseline (228.049 us; speedup 1.0000x reference)
//
#include <hip/hip_runtime.h>

#define NB 256
#define NT 1024
#define NL 64

typedef __fp16 h2v __attribute__((ext_vector_type(2)));

__device__ __forceinline__ float rfl_f(float v) {
  return __builtin_bit_cast(float, __builtin_amdgcn_readfirstlane(__builtin_bit_cast(int, v)));
}

// DPP self-permute: result[l] = v[l ^ mask] for the xor-type ctrl codes used below.
#define DPPI(V, C) __builtin_amdgcn_update_dpp(V, V, C, 0xF, 0xF, false)

// One CRF step, all-register broadcast version (no LDS on the critical path).
//
// Gather: butterfly over xor-masks {32,16,15,7,3,1} (full rank over GF(2)^6):
//   permlane32_swap(w,w)  -> u0 = w[l&~32], u1 = w[l|32]
//   permlane16_swap(u,u)  -> v_j[l] = w[(l&15) + 16j],  j=0..3
//   pack (v0,v1),(v2,v3)  -> P[0] = (w[b], w[b+16]), P[1] = (w[b+32], w[b+48]), b = l&15
//   DPP ^15, ^7, ^3, ^1 on packed regs -> 32 packed regs covering all 64 values,
//   at per-lane base index b = (l&15) ^ m_seq[i]  (lane-dependent order, matched
//   by the per-lane Rh load order at setup).
// Renorm: K = 2^(115 - e8) from the f32 exponent of lane0's w (readfirstlane,
// uniform, off the critical chain; arithmetic identical to the old f16-exponent
// scheme: e5 = e8-112 -> 2^(3-e5) = 2^(115-e8), e2 += e8-115).
#define CRF_STEP(EF)                                                          \
  do {                                                                        \
    int wi = __builtin_bit_cast(int, w);                                      \
    int e8 = (__builtin_amdgcn_readfirstlane(wi) >> 23) & 0xff;               \
    float K = __builtin_bit_cast(float, (242 - e8) << 23);                    \
    float KE = K * (EF);                                                      \
    e2 += e8 - 115;                                                           \
    auto u = __builtin_amdgcn_permlane32_swap(wi, wi, false, false);          \
    auto va = __builtin_amdgcn_permlane16_swap(u[0], u[0], false, false);     \
    auto vb = __builtin_amdgcn_permlane16_swap(u[1], u[1], false, false);     \
    int P[32];                                                                \
    P[0] = __builtin_bit_cast(int, __builtin_amdgcn_cvt_pkrtz(                \
               __builtin_bit_cast(float, va[0]),                              \
               __builtin_bit_cast(float, va[1])));                            \
    P[1] = __builtin_bit_cast(int, __builtin_amdgcn_cvt_pkrtz(                \
               __builtin_bit_cast(float, vb[0]),                              \
               __builtin_bit_cast(float, vb[1])));                            \
    P[2] = DPPI(P[0], 0x140); /* row_mirror: ^15 */                           \
    P[3] = DPPI(P[1], 0x140);                                                 \
    _Pragma("unroll")                                                         \
    for (int k = 0; k < 4; k++) P[4 + k] = DPPI(P[k], 0x141); /* ^7 */        \
    _Pragma("unroll")                                                         \
    for (int k = 0; k < 8; k++) P[8 + k] = DPPI(P[k], 0x1B); /* ^3 */         \
    _Pragma("unroll")                                                         \
    for (int k = 0; k < 16; k++) P[16 + k] = DPPI(P[k], 0xB1); /* ^1 */       \
    float s0 = 0.f, s1 = 0.f, s2 = 0.f, s3 = 0.f;                             \
    _Pragma("unroll")                                                         \
    for (int k = 0; k < 32; k += 4) {                                         \
      s0 = __builtin_amdgcn_fdot2(__builtin_bit_cast(h2v, P[k + 0]), Rh[k + 0], s0, false); \
      s1 = __builtin_amdgcn_fdot2(__builtin_bit_cast(h2v, P[k + 1]), Rh[k + 1], s1, false); \
      s2 = __builtin_amdgcn_fdot2(__builtin_bit_cast(h2v, P[k + 2]), Rh[k + 2], s2, false); \
      s3 = __builtin_amdgcn_fdot2(__builtin_bit_cast(h2v, P[k + 3]), Rh[k + 3], s3, false); \
    }                                                                         \
    w = ((s0 + s1) + (s2 + s3)) * KE;                                         \
  } while (0)

// Blocks 0..255: forward chains. 256..511: backward chains. 512..767: gold path
// (hides under the fb waves co-resident on the same CUs).
__global__ __launch_bounds__(64) void fb_kernel(const float* __restrict__ scores,
                                                const int* __restrict__ targets,
                                                const float* __restrict__ start,
                                                const float* __restrict__ Tm,
                                                const float* __restrict__ endv,
                                                float* __restrict__ wsA,
                                                float* __restrict__ wsB,
                                                float* __restrict__ wsG) {
  const int lane = threadIdx.x;
  const int bb = blockIdx.x;

  if (bb >= 2 * NB) {  // ---- gold path: one wave per batch ----
    const int b = bb - 2 * NB;
    const int* tg = targets + b * NT;
    const float* sc = scores + (size_t)b * NT * NL;
    float acc = 0.f;
    for (int t = lane; t < NT; t += 64) {
      int c = tg[t];
      acc += sc[t * NL + c];
      if (t > 0) acc += Tm[c * NL + tg[t - 1]];  // T_mat[cur, prev]
    }
#pragma unroll
    for (int off = 32; off > 0; off >>= 1) acc += __shfl_xor(acc, off, 64);
    if (lane == 0) wsG[b] = acc + start[tg[0]] + endv[tg[NT - 1]];
    return;
  }

  const bool bwd = bb >= NB;
  const int b = bwd ? bb - NB : bb;
  const float* sc = scores + (size_t)b * NT * NL;
  const float LN2 = 0.69314718055994530942f;

  // Per-lane gather ordering: pair i holds base index (lane&15) ^ m_seq[i],
  // slot 2i = prevs (base, base+16), slot 2i+1 = prevs (base+32, base+48).
  // m_seq is the DPP generation order: {0,15}, ^7, ^3, ^1 applied in sequence.
  constexpr int m_seq[16] = {0, 15, 7, 8, 3, 12, 4, 11, 1, 14, 6, 9, 2, 13, 5, 10};

  // f16 transition table, in gather order:
  //  fwd r(p) = exp(T[lane][p])   (Tb = Tm + lane*NL, str = 1)
  //  bwd r(p) = exp(T[p][lane])   (Tb = Tm + lane,    str = NL)
  const float* Tb = bwd ? (Tm + lane) : (Tm + lane * NL);
  const int str = bwd ? NL : 1;
  h2v Rh[32];
#pragma unroll
  for (int i = 0; i < 16; i++) {
    int base = (lane & 15) ^ m_seq[i];
    Rh[2 * i + 0] = __builtin_amdgcn_cvt_pkrtz(__expf(Tb[(base + 0) * str]),
                                               __expf(Tb[(base + 16) * str]));
    Rh[2 * i + 1] = __builtin_amdgcn_cvt_pkrtz(__expf(Tb[(base + 32) * str]),
                                               __expf(Tb[(base + 48) * str]));
  }

  if (!bwd) {
    float a0 = start[lane] + sc[lane];  // alpha_0
    float m0 = rfl_f(a0);
    float w = __expf(a0 - m0) * 16.f;   // keep w_0 in f16-normal range
    int e2 = -4;

    float buf[4];
#pragma unroll
    for (int k = 0; k < 4; k++) buf[k] = sc[(1 + k) * NL + lane];

    for (int i = 0; i < 128; i++) {  // 512 steps: t = 1..512
      float nb4[4];
      int tb = 5 + 4 * i;  // prefetch (max t=516 < 1024)
#pragma unroll
      for (int k = 0; k < 4; k++) nb4[k] = sc[(tb + k) * NL + lane];
      float Ev[4];
#pragma unroll
      for (int k = 0; k < 4; k++) Ev[k] = __expf(buf[k]);  // off critical chain
      CRF_STEP(Ev[0]);
      CRF_STEP(Ev[1]);
      CRF_STEP(Ev[2]);
      CRF_STEP(Ev[3]);
#pragma unroll
      for (int k = 0; k < 4; k++) buf[k] = nb4[k];
    }
    wsA[lane * NB + b] = m0 + (float)e2 * LN2 + __logf(w);  // alpha_512 (transposed)
  } else {
    float a0 = endv[lane] + sc[(NT - 1) * NL + lane];
    float m0 = rfl_f(a0);
    float w = __expf(a0 - m0) * 16.f;
    int e2 = -4;

    float buf[4];
#pragma unroll
    for (int k = 0; k < 4; k++) buf[k] = sc[(1022 - k) * NL + lane];

    for (int i = 0; i < 127; i++) {  // 508 steps: te = 1022..515
      float nb4[4];
      int tb = 1018 - 4 * i;  // prefetch (min 511 >= 0)
#pragma unroll
      for (int k = 0; k < 4; k++) nb4[k] = sc[(tb - k) * NL + lane];
      float Ev[4];
#pragma unroll
      for (int k = 0; k < 4; k++) Ev[k] = __expf(buf[k]);
      CRF_STEP(Ev[0]);
      CRF_STEP(Ev[1]);
      CRF_STEP(Ev[2]);
      CRF_STEP(Ev[3]);
#pragma unroll
      for (int k = 0; k < 4; k++) buf[k] = nb4[k];
    }
    CRF_STEP(__expf(sc[514 * NL + lane]));
    CRF_STEP(__expf(sc[513 * NL + lane]));
    CRF_STEP(1.0f);  // final matvec-only step -> beta_512
    wsB[lane * NB + b] = m0 + (float)e2 * LN2 + __logf(w);  // beta_512 (transposed)
  }
}

// thread b handles batch b: lse over 64 states (coalesced via transposed ws layout),
// subtract gold, block-reduce mean.
__global__ __launch_bounds__(256) void combine_kernel(const float* __restrict__ wsA,
                                                      const float* __restrict__ wsB,
                                                      const float* __restrict__ wsG,
                                                      float* __restrict__ out) {
  const int b = threadIdx.x;
  float m = -INFINITY;
#pragma unroll
  for (int j = 0; j < NL; j++) m = fmaxf(m, wsA[j * NB + b] + wsB[j * NB + b]);
  float s = 0.f;
#pragma unroll
  for (int j = 0; j < NL; j++) s += __expf(wsA[j * NB + b] + wsB[j * NB + b] - m);
  float loss = (m + __logf(s)) - wsG[b];
#pragma unroll
  for (int off = 32; off > 0; off >>= 1) loss += __shfl_xor(loss, off, 64);
  __shared__ float red[4];
  if ((b & 63) == 0) red[b >> 6] = loss;
  __syncthreads();
  if (b == 0) out[0] = (red[0] + red[1] + red[2] + red[3]) * (1.0f / NB);
}

extern "C" void kernel_launch(void* const* d_in, const int* in_sizes, int n_in,
                              void* d_out, int out_size, void* d_ws, size_t ws_size,
                              hipStream_t stream) {
  const float* scores = (const float*)d_in[0];
  const int* targets = (const int*)d_in[1];
  const float* start = (const float*)d_in[2];
  const float* Tm = (const float*)d_in[3];
  const float* endv = (const float*)d_in[4];
  float* out = (float*)d_out;

  float* wsA = (float*)d_ws;       // [NL*NB] alpha_512, transposed [state][batch]
  float* wsB = wsA + NB * NL;      // [NL*NB] beta_512, transposed
  float* wsG = wsB + NB * NL;      // [NB] gold path scores

  fb_kernel<<<3 * NB, 64, 0, stream>>>(scores, targets, start, Tm, endv, wsA, wsB, wsG);
  combine_kernel<<<1, 256, 0, stream>>>(wsA, wsB, wsG, out);
}